// Round 1
// baseline (2121.539 us; speedup 1.0000x reference)
//
#include <hip/hip_runtime.h>

#define NN 100000
#define EE 1600000
#define F0 500
#define F1 256
#define F2 128
#define F3 40
#define KITER 10

// ---------------------------------------------------------------------------
// Tiled fp32 GEMM: C[i,j] = relu(sum_k A[i,k] * W[j,k] + bias[j])
// A: [nrows, K] row-major, W: [M, K] row-major (PyTorch convention)
// ---------------------------------------------------------------------------
template<int BM, int BN, int BK>
__global__ __launch_bounds__(256)
void gemm_relu_kernel(const float* __restrict__ A, const float* __restrict__ W,
                      const float* __restrict__ bias, float* __restrict__ C,
                      int nrows, int K, int M) {
    __shared__ float As[BK][BM + 4];
    __shared__ float Ws[BK][BN + 4];
    const int tid = threadIdx.x;
    const int tx = tid & 15;   // col group 0..15
    const int ty = tid >> 4;   // row group 0..15
    const int rowBase = blockIdx.y * BM;
    const int colBase = blockIdx.x * BN;

    const int lk = tid & 15;   // k index within tile (BK == 16)
    const int lr = tid >> 4;   // row/col index for loading

    float acc[4][4] = {};

    for (int k0 = 0; k0 < K; k0 += BK) {
        const int gk = k0 + lk;
        #pragma unroll
        for (int it = 0; it < BM / 16; ++it) {
            int r = lr + it * 16;
            int grow = rowBase + r;
            float v = 0.f;
            if (grow < nrows && gk < K) v = A[(size_t)grow * K + gk];
            As[lk][r] = v;
        }
        #pragma unroll
        for (int it = 0; it < BN / 16; ++it) {
            int c = lr + it * 16;
            int gcol = colBase + c;
            float v = 0.f;
            if (gcol < M && gk < K) v = W[(size_t)gcol * K + gk];
            Ws[lk][c] = v;
        }
        __syncthreads();
        #pragma unroll
        for (int kk = 0; kk < BK; ++kk) {
            float4 a = *(const float4*)&As[kk][ty * 4];
            float4 w = *(const float4*)&Ws[kk][tx * 4];
            float av[4] = {a.x, a.y, a.z, a.w};
            float wv[4] = {w.x, w.y, w.z, w.w};
            #pragma unroll
            for (int i = 0; i < 4; ++i)
                #pragma unroll
                for (int j = 0; j < 4; ++j)
                    acc[i][j] = fmaf(av[i], wv[j], acc[i][j]);
        }
        __syncthreads();
    }

    #pragma unroll
    for (int i = 0; i < 4; ++i) {
        int grow = rowBase + ty * 4 + i;
        if (grow >= nrows) continue;
        #pragma unroll
        for (int j = 0; j < 4; ++j) {
            int gcol = colBase + tx * 4 + j;
            if (gcol >= M) continue;
            float v = acc[i][j] + bias[gcol];
            C[(size_t)grow * M + gcol] = v > 0.f ? v : 0.f;
        }
    }
}

// ---------------------------------------------------------------------------
// Graph build: degree (with self-loop), dinv, CSR-by-dst via scan + atomic fill
// ---------------------------------------------------------------------------
__global__ void deg_init_kernel(int* deg, int n) {
    int i = blockIdx.x * blockDim.x + threadIdx.x;
    if (i < n) deg[i] = 1;  // self-loop
}

__global__ void deg_count_kernel(const int* __restrict__ dst, int* deg, int e) {
    int i = blockIdx.x * blockDim.x + threadIdx.x;
    if (i < e) atomicAdd(&deg[dst[i]], 1);
}

__global__ void dinv_kernel(const int* __restrict__ deg, float* __restrict__ dinv,
                            float* __restrict__ dinv2, int n) {
    int i = blockIdx.x * blockDim.x + threadIdx.x;
    if (i < n) {
        float d = (float)deg[i];
        dinv[i] = rsqrtf(d);
        dinv2[i] = 1.0f / d;
    }
}

// counts[v] = deg[v]-1 (real in-edges). 2048 elements per block.
__global__ __launch_bounds__(256)
void scan1_kernel(const int* __restrict__ deg, int* __restrict__ row_ptr,
                  int* __restrict__ blockSums, int n) {
    __shared__ int sdata[256];
    const int base = blockIdx.x * 2048;
    const int t = threadIdx.x;
    int local[8];
    int s = 0;
    #pragma unroll
    for (int i = 0; i < 8; ++i) {
        int idx = base + t * 8 + i;
        int c = (idx < n) ? (deg[idx] - 1) : 0;
        local[i] = s;   // exclusive within thread
        s += c;
    }
    sdata[t] = s;
    __syncthreads();
    for (int off = 1; off < 256; off <<= 1) {
        int v = (t >= off) ? sdata[t - off] : 0;
        __syncthreads();
        sdata[t] += v;
        __syncthreads();
    }
    int excl = (t == 0) ? 0 : sdata[t - 1];
    #pragma unroll
    for (int i = 0; i < 8; ++i) {
        int idx = base + t * 8 + i;
        if (idx < n) row_ptr[idx] = excl + local[i];
    }
    if (t == 255) blockSums[blockIdx.x] = sdata[255];
}

__global__ void scan2_kernel(int* blockSums, int nb) {
    if (threadIdx.x == 0 && blockIdx.x == 0) {
        int s = 0;
        for (int i = 0; i < nb; ++i) { int v = blockSums[i]; blockSums[i] = s; s += v; }
    }
}

__global__ void scan3_kernel(int* __restrict__ row_ptr, int* __restrict__ cursor,
                             const int* __restrict__ blockSums, int n, int e) {
    int i = blockIdx.x * blockDim.x + threadIdx.x;
    if (i < n) {
        int v = row_ptr[i] + blockSums[i >> 11];
        row_ptr[i] = v;
        cursor[i] = v;
    }
    if (i == 0) row_ptr[n] = e;
}

__global__ void fill_csr_kernel(const int* __restrict__ src, const int* __restrict__ dst,
                                const float* __restrict__ dinv, int* cursor,
                                int* __restrict__ csr_src, float* __restrict__ csr_norm,
                                int e) {
    int i = blockIdx.x * blockDim.x + threadIdx.x;
    if (i < e) {
        int s = src[i], d = dst[i];
        int pos = atomicAdd(&cursor[d], 1);
        csr_src[pos] = s;
        csr_norm[pos] = dinv[s] * dinv[d];
    }
}

// ---------------------------------------------------------------------------
// One APPNP step: hout = 0.9*(dinv2[v]*hin[v] + sum_e hin[src]*norm) + 0.1*h0[v]
// block = 320 threads = 8 nodes x 40 features
// ---------------------------------------------------------------------------
__global__ __launch_bounds__(320)
void prop_kernel(const float* __restrict__ hin, const float* __restrict__ h0,
                 const int* __restrict__ row_ptr, const int* __restrict__ csr_src,
                 const float* __restrict__ csr_norm, const float* __restrict__ dinv2,
                 float* __restrict__ hout, int n) {
    const int t = threadIdx.x;
    const int vl = t / 40;
    const int f = t - vl * 40;
    const int v = blockIdx.x * 8 + vl;
    if (v >= n) return;
    float acc = dinv2[v] * hin[(size_t)v * 40 + f];
    const int e0 = row_ptr[v];
    const int e1 = row_ptr[v + 1];
    for (int e = e0; e < e1; ++e) {
        int s = csr_src[e];
        float w = csr_norm[e];
        acc = fmaf(hin[(size_t)s * 40 + f], w, acc);
    }
    hout[(size_t)v * 40 + f] = fmaf(0.9f, acc, 0.1f * h0[(size_t)v * 40 + f]);
}

// ---------------------------------------------------------------------------
extern "C" void kernel_launch(void* const* d_in, const int* in_sizes, int n_in,
                              void* d_out, int out_size, void* d_ws, size_t ws_size,
                              hipStream_t stream) {
    const float* x  = (const float*)d_in[0];
    const int* ei   = (const int*)d_in[1];
    const float* W0 = (const float*)d_in[2];
    const float* b0 = (const float*)d_in[3];
    const float* W1 = (const float*)d_in[4];
    const float* b1 = (const float*)d_in[5];
    const float* W2 = (const float*)d_in[6];
    const float* b2 = (const float*)d_in[7];
    float* out = (float*)d_out;
    char* ws = (char*)d_ws;

    const int* src = ei;        // edge_index[0, :]
    const int* dst = ei + EE;   // edge_index[1, :]

    // Workspace layout (bytes). h1 region [0, 102.4e6) is reused after GEMM1.
    float* h1   = (float*)(ws);                   // [N,256] = 102,400,000 B
    float* h2   = (float*)(ws + 102400000);       // [N,128] =  51,200,000 B (ends 153.6e6)
    float* h0   = (float*)(ws);                   // [N,40]  = 16,000,000 B (reuses dead h1)
    float* hA   = (float*)(ws + 16000000);        // [N,40]
    float* hB   = (float*)(ws + 32000000);        // [N,40]
    int*   deg  = (int*)  (ws + 48000000);        // [N]
    float* dinv = (float*)(ws + 48400000);        // [N]
    float* dnv2 = (float*)(ws + 48800000);        // [N]
    int*   rowp = (int*)  (ws + 49200000);        // [N+1]
    int*   curs = (int*)  (ws + 49600016);        // [N]
    int*   bsum = (int*)  (ws + 50000016);        // [<=4096]
    int*   csrc = (int*)  (ws + 50016400);        // [E]
    float* cnrm = (float*)(ws + 56416400);        // [E] (ends 62,816,400)
    (void)ws_size; (void)in_sizes; (void)n_in; (void)out_size;

    // ---- MLP encoder ----
    {
        dim3 blk(256);
        dim3 g0((F1 + 63) / 64, (NN + 63) / 64);
        gemm_relu_kernel<64, 64, 16><<<g0, blk, 0, stream>>>(x, W0, b0, h1, NN, F0, F1);
        dim3 g1((F2 + 63) / 64, (NN + 63) / 64);
        gemm_relu_kernel<64, 64, 16><<<g1, blk, 0, stream>>>(h1, W1, b1, h2, NN, F1, F2);
        dim3 g2((F3 + 63) / 64, (NN + 63) / 64);
        gemm_relu_kernel<64, 64, 16><<<g2, blk, 0, stream>>>(h2, W2, b2, h0, NN, F2, F3);
    }

    // ---- Graph build (CSR by dst) ----
    {
        int nb_n = (NN + 255) / 256;
        int nb_e = (EE + 255) / 256;
        deg_init_kernel<<<nb_n, 256, 0, stream>>>(deg, NN);
        deg_count_kernel<<<nb_e, 256, 0, stream>>>(dst, deg, EE);
        dinv_kernel<<<nb_n, 256, 0, stream>>>(deg, dinv, dnv2, NN);
        int nb_scan = (NN + 2047) / 2048;  // 49
        scan1_kernel<<<nb_scan, 256, 0, stream>>>(deg, rowp, bsum, NN);
        scan2_kernel<<<1, 64, 0, stream>>>(bsum, nb_scan);
        scan3_kernel<<<nb_n, 256, 0, stream>>>(rowp, curs, bsum, NN, EE);
        fill_csr_kernel<<<nb_e, 256, 0, stream>>>(src, dst, dinv, curs, csrc, cnrm, EE);
    }

    // ---- APPNP propagation, K = 10 ----
    {
        dim3 blk(320);
        dim3 grd((NN + 7) / 8);  // 12500
        const float* hin = h0;
        for (int it = 0; it < KITER; ++it) {
            float* hout = (it == KITER - 1) ? out : ((it & 1) ? hB : hA);
            prop_kernel<<<grd, blk, 0, stream>>>(hin, h0, rowp, csrc, cnrm, dnv2, hout, NN);
            hin = hout;
        }
    }
}

// Round 2
// 1665.520 us; speedup vs baseline: 1.2738x; 1.2738x over previous
//
#include <hip/hip_runtime.h>

#define NN 100000
#define EE 1600000
#define KITER 10

typedef __attribute__((ext_vector_type(8))) short s16x8;
typedef __attribute__((ext_vector_type(4))) float f32x4;

__device__ __forceinline__ short f2bf(float f) {
    union { float f; unsigned u; } v; v.f = f;
    unsigned r = v.u + 0x7FFFu + ((v.u >> 16) & 1u);   // RNE
    return (short)(r >> 16);
}

__device__ __forceinline__ void gload_lds16(const void* g, void* l) {
    __builtin_amdgcn_global_load_lds(
        (const __attribute__((address_space(1))) void*)g,
        (__attribute__((address_space(3))) void*)l, 16, 0, 0);
}

// ---------------------------------------------------------------------------
// bf16 MFMA GEMM: C = relu(A @ W^T + bias). Tile 128x128, 4 waves, 16x16x32.
// MODE 0: A is fp32 [nrows][KREAL], converted in-register during staging
//         (K zero-padded to KSTEPS*32).
// MODE 1: A is bf16 [nrows][KSTEPS*32] staged via global_load_lds width=16.
// B (weights) always bf16 [M][KSTEPS*32], row-major, zero-padded.
// ---------------------------------------------------------------------------
template<int MODE, int KSTEPS, int KREAL, bool OUT_BF16>
__global__ __launch_bounds__(256)
void mfma_gemm(const void* __restrict__ Ain, const short* __restrict__ B,
               const float* __restrict__ bias, int nbias,
               void* __restrict__ Cout, int ldc, int ncols_store, int nrows)
{
    __shared__ short ldsA[128 * 32];
    __shared__ short ldsB[128 * 32];
    const int t    = threadIdx.x;
    const int lane = t & 63;
    const int wid  = t >> 6;
    const int rowBase = blockIdx.y * 128;
    const int colBase = blockIdx.x * 128;
    const int wrow = (wid >> 1) * 64;
    const int wcol = (wid & 1) * 64;

    const int q  = t & 3;    // 8-elem chunk within 32-wide k tile
    const int rl = t >> 2;   // 0..63

    f32x4 acc[4][4] = {};

    const int KP = KSTEPS * 32;

    for (int ks = 0; ks < KSTEPS; ++ks) {
        const int k0 = ks * 32;

        // ---- stage B tile: cols [colBase,+128) x k [k0,+32), bf16 ----
        #pragma unroll
        for (int i = 0; i < 2; ++i) {
            const short* src = B + (size_t)(colBase + rl + i * 64) * KP + k0 + q * 8;
            gload_lds16(src, &ldsB[wid * 512 + i * 2048]);  // +lane*16B by HW
        }

        // ---- stage A tile: rows [rowBase,+128) x k [k0,+32) ----
        if constexpr (MODE == 0) {
            const float* Af = (const float*)Ain;
            #pragma unroll
            for (int i = 0; i < 2; ++i) {
                int rloc = rl + i * 64;
                int grow = rowBase + rloc; if (grow > NN - 1) grow = NN - 1;
                int gk = k0 + q * 8;
                float v[8];
                if (gk + 8 <= KREAL) {
                    const float4* p = (const float4*)(Af + (size_t)grow * KREAL + gk);
                    float4 u0 = p[0], u1 = p[1];
                    v[0]=u0.x; v[1]=u0.y; v[2]=u0.z; v[3]=u0.w;
                    v[4]=u1.x; v[5]=u1.y; v[6]=u1.z; v[7]=u1.w;
                } else {
                    #pragma unroll
                    for (int j = 0; j < 8; ++j) {
                        int g = gk + j;
                        v[j] = (g < KREAL) ? Af[(size_t)grow * KREAL + g] : 0.f;
                    }
                }
                s16x8 s;
                #pragma unroll
                for (int j = 0; j < 8; ++j) s[j] = f2bf(v[j]);
                *(s16x8*)&ldsA[rloc * 32 + q * 8] = s;
            }
        } else {
            const short* Ab = (const short*)Ain;
            #pragma unroll
            for (int i = 0; i < 2; ++i) {
                int grow = rowBase + rl + i * 64; if (grow > NN - 1) grow = NN - 1;
                const short* src = Ab + (size_t)grow * KP + k0 + q * 8;
                gload_lds16(src, &ldsA[wid * 512 + i * 2048]);
            }
        }

        __syncthreads();

        // ---- fragments + MFMA ----
        {
            const int kb = lane >> 4;     // 0..3 -> k sub-offset kb*8
            const int l16 = lane & 15;
            s16x8 a[4], b[4];
            #pragma unroll
            for (int m = 0; m < 4; ++m)
                a[m] = *(const s16x8*)&ldsA[(wrow + m * 16 + l16) * 32 + kb * 8];
            #pragma unroll
            for (int n = 0; n < 4; ++n)
                b[n] = *(const s16x8*)&ldsB[(wcol + n * 16 + l16) * 32 + kb * 8];
            #pragma unroll
            for (int m = 0; m < 4; ++m)
                #pragma unroll
                for (int n = 0; n < 4; ++n)
                    acc[m][n] = __builtin_amdgcn_mfma_f32_16x16x32_bf16(
                        a[m], b[n], acc[m][n], 0, 0, 0);
        }

        __syncthreads();
    }

    // ---- epilogue: bias + relu, store ----
    const int crow0 = (lane >> 4) * 4;
    const int ccol  = lane & 15;
    #pragma unroll
    for (int n = 0; n < 4; ++n) {
        int col = colBase + wcol + n * 16 + ccol;
        float bv = (col < nbias) ? bias[col] : 0.f;
        #pragma unroll
        for (int m = 0; m < 4; ++m) {
            #pragma unroll
            for (int j = 0; j < 4; ++j) {
                int row = rowBase + wrow + m * 16 + crow0 + j;
                if (row >= nrows) continue;
                float v = acc[m][n][j] + bv;
                v = fmaxf(v, 0.f);
                if (OUT_BF16) {
                    ((short*)Cout)[(size_t)row * ldc + col] = f2bf(v);
                } else if (col < ncols_store) {
                    ((float*)Cout)[(size_t)row * ldc + col] = v;
                }
            }
        }
    }
}

// ---------------------------------------------------------------------------
// Weight convert + zero-pad: in fp32 [R][C] -> out bf16 [Rp][Cp]
// ---------------------------------------------------------------------------
__global__ void convert_w_kernel(const float* __restrict__ in, short* __restrict__ out,
                                 int R, int C, int Rp, int Cp) {
    int idx = blockIdx.x * blockDim.x + threadIdx.x;
    if (idx >= Rp * Cp) return;
    int r = idx / Cp, c = idx - r * Cp;
    float v = (r < R && c < C) ? in[r * C + c] : 0.f;
    out[idx] = f2bf(v);
}

// ---------------------------------------------------------------------------
// Graph build (unchanged from round 1)
// ---------------------------------------------------------------------------
__global__ void deg_init_kernel(int* deg, int n) {
    int i = blockIdx.x * blockDim.x + threadIdx.x;
    if (i < n) deg[i] = 1;
}
__global__ void deg_count_kernel(const int* __restrict__ dst, int* deg, int e) {
    int i = blockIdx.x * blockDim.x + threadIdx.x;
    if (i < e) atomicAdd(&deg[dst[i]], 1);
}
__global__ void dinv_kernel(const int* __restrict__ deg, float* __restrict__ dinv,
                            float* __restrict__ dinv2, int n) {
    int i = blockIdx.x * blockDim.x + threadIdx.x;
    if (i < n) {
        float d = (float)deg[i];
        dinv[i] = rsqrtf(d);
        dinv2[i] = 1.0f / d;
    }
}
__global__ __launch_bounds__(256)
void scan1_kernel(const int* __restrict__ deg, int* __restrict__ row_ptr,
                  int* __restrict__ blockSums, int n) {
    __shared__ int sdata[256];
    const int base = blockIdx.x * 2048;
    const int t = threadIdx.x;
    int local[8];
    int s = 0;
    #pragma unroll
    for (int i = 0; i < 8; ++i) {
        int idx = base + t * 8 + i;
        int c = (idx < n) ? (deg[idx] - 1) : 0;
        local[i] = s;
        s += c;
    }
    sdata[t] = s;
    __syncthreads();
    for (int off = 1; off < 256; off <<= 1) {
        int v = (t >= off) ? sdata[t - off] : 0;
        __syncthreads();
        sdata[t] += v;
        __syncthreads();
    }
    int excl = (t == 0) ? 0 : sdata[t - 1];
    #pragma unroll
    for (int i = 0; i < 8; ++i) {
        int idx = base + t * 8 + i;
        if (idx < n) row_ptr[idx] = excl + local[i];
    }
    if (t == 255) blockSums[blockIdx.x] = sdata[255];
}
__global__ void scan2_kernel(int* blockSums, int nb) {
    if (threadIdx.x == 0 && blockIdx.x == 0) {
        int s = 0;
        for (int i = 0; i < nb; ++i) { int v = blockSums[i]; blockSums[i] = s; s += v; }
    }
}
__global__ void scan3_kernel(int* __restrict__ row_ptr, int* __restrict__ cursor,
                             const int* __restrict__ blockSums, int n, int e) {
    int i = blockIdx.x * blockDim.x + threadIdx.x;
    if (i < n) {
        int v = row_ptr[i] + blockSums[i >> 11];
        row_ptr[i] = v;
        cursor[i] = v;
    }
    if (i == 0) row_ptr[n] = e;
}
__global__ void fill_csr_kernel(const int* __restrict__ src, const int* __restrict__ dst,
                                const float* __restrict__ dinv, int* cursor,
                                int* __restrict__ csr_src, float* __restrict__ csr_norm,
                                int e) {
    int i = blockIdx.x * blockDim.x + threadIdx.x;
    if (i < e) {
        int s = src[i], d = dst[i];
        int pos = atomicAdd(&cursor[d], 1);
        csr_src[pos] = s;
        csr_norm[pos] = dinv[s] * dinv[d];
    }
}

// ---------------------------------------------------------------------------
// APPNP step (unchanged)
// ---------------------------------------------------------------------------
__global__ __launch_bounds__(320)
void prop_kernel(const float* __restrict__ hin, const float* __restrict__ h0,
                 const int* __restrict__ row_ptr, const int* __restrict__ csr_src,
                 const float* __restrict__ csr_norm, const float* __restrict__ dinv2,
                 float* __restrict__ hout, int n) {
    const int t = threadIdx.x;
    const int vl = t / 40;
    const int f = t - vl * 40;
    const int v = blockIdx.x * 8 + vl;
    if (v >= n) return;
    float acc = dinv2[v] * hin[(size_t)v * 40 + f];
    const int e0 = row_ptr[v];
    const int e1 = row_ptr[v + 1];
    for (int e = e0; e < e1; ++e) {
        int s = csr_src[e];
        float w = csr_norm[e];
        acc = fmaf(hin[(size_t)s * 40 + f], w, acc);
    }
    hout[(size_t)v * 40 + f] = fmaf(0.9f, acc, 0.1f * h0[(size_t)v * 40 + f]);
}

// ---------------------------------------------------------------------------
extern "C" void kernel_launch(void* const* d_in, const int* in_sizes, int n_in,
                              void* d_out, int out_size, void* d_ws, size_t ws_size,
                              hipStream_t stream) {
    const float* x  = (const float*)d_in[0];
    const int* ei   = (const int*)d_in[1];
    const float* W0 = (const float*)d_in[2];
    const float* b0 = (const float*)d_in[3];
    const float* W1 = (const float*)d_in[4];
    const float* b1 = (const float*)d_in[5];
    const float* W2 = (const float*)d_in[6];
    const float* b2 = (const float*)d_in[7];
    float* out = (float*)d_out;
    char* ws = (char*)d_ws;

    const int* src = ei;
    const int* dst = ei + EE;

    // Workspace layout (bytes), total ~140.0 MB
    short* W0b  = (short*)(ws + 0);          // [256][512]  262144
    short* W1b  = (short*)(ws + 262144);     // [128][256]   65536
    short* W2b  = (short*)(ws + 327680);     // [128][128]   32768
    int*   deg  = (int*)  (ws + 360448);     // [N]
    float* dinv = (float*)(ws + 760448);     // [N]
    float* dnv2 = (float*)(ws + 1160448);    // [N]
    int*   rowp = (int*)  (ws + 1560448);    // [N+1]
    int*   curs = (int*)  (ws + 1960452);    // [N]
    int*   bsum = (int*)  (ws + 2360452);    // [4096]
    int*   csrc = (int*)  (ws + 2376836);    // [E]
    float* cnrm = (float*)(ws + 8776836);    // [E]          -> 15176836
    short* h1b  = (short*)(ws + 15176960);   // [N][256] bf16 -> 66376960
    short* h2b  = (short*)(ws + 66376960);   // [N][128] bf16 -> 91976960
    float* h0   = (float*)(ws + 91976960);   // [N][40]  f32  -> 107976960
    float* hA   = (float*)(ws + 107976960);  // [N][40]
    float* hB   = (float*)(ws + 123976960);  // [N][40]  -> 139976960
    (void)ws_size; (void)in_sizes; (void)n_in; (void)out_size;

    // ---- weight conversion (tiny) ----
    convert_w_kernel<<<(256 * 512 + 255) / 256, 256, 0, stream>>>(W0, W0b, 256, 500, 256, 512);
    convert_w_kernel<<<(128 * 256 + 255) / 256, 256, 0, stream>>>(W1, W1b, 128, 256, 128, 256);
    convert_w_kernel<<<(128 * 128 + 255) / 256, 256, 0, stream>>>(W2, W2b, 40, 128, 128, 128);

    // ---- MLP encoder: bf16 MFMA GEMMs ----
    const int NBLK = (NN + 127) / 128;  // 782
    mfma_gemm<0, 16, 500, true ><<<dim3(2, NBLK), 256, 0, stream>>>(
        (const void*)x, W0b, b0, 256, (void*)h1b, 256, 256, NN);
    mfma_gemm<1, 8, 256, true ><<<dim3(1, NBLK), 256, 0, stream>>>(
        (const void*)h1b, W1b, b1, 128, (void*)h2b, 128, 128, NN);
    mfma_gemm<1, 4, 128, false><<<dim3(1, NBLK), 256, 0, stream>>>(
        (const void*)h2b, W2b, b2, 40, (void*)h0, 40, 40, NN);

    // ---- graph build ----
    {
        int nb_n = (NN + 255) / 256;
        int nb_e = (EE + 255) / 256;
        deg_init_kernel<<<nb_n, 256, 0, stream>>>(deg, NN);
        deg_count_kernel<<<nb_e, 256, 0, stream>>>(dst, deg, EE);
        dinv_kernel<<<nb_n, 256, 0, stream>>>(deg, dinv, dnv2, NN);
        int nb_scan = (NN + 2047) / 2048;
        scan1_kernel<<<nb_scan, 256, 0, stream>>>(deg, rowp, bsum, NN);
        scan2_kernel<<<1, 64, 0, stream>>>(bsum, nb_scan);
        scan3_kernel<<<nb_n, 256, 0, stream>>>(rowp, curs, bsum, NN, EE);
        fill_csr_kernel<<<nb_e, 256, 0, stream>>>(src, dst, dinv, curs, csrc, cnrm, EE);
    }

    // ---- APPNP propagation ----
    {
        dim3 blk(320);
        dim3 grd((NN + 7) / 8);
        const float* hin = h0;
        for (int it = 0; it < KITER; ++it) {
            float* hout = (it == KITER - 1) ? out : ((it & 1) ? hB : hA);
            prop_kernel<<<grd, blk, 0, stream>>>(hin, h0, rowp, csrc, cnrm, dnv2, hout, NN);
            hin = hout;
        }
    }
}

// Round 3
// 895.647 us; speedup vs baseline: 2.3687x; 1.8596x over previous
//
#include <hip/hip_runtime.h>

#define NN 100000
#define EE 1600000
#define KITER 10

typedef __attribute__((ext_vector_type(8))) short s16x8;
typedef __attribute__((ext_vector_type(4))) float f32x4;

__device__ __forceinline__ short f2bf(float f) {
    union { float f; unsigned u; } v; v.f = f;
    unsigned r = v.u + 0x7FFFu + ((v.u >> 16) & 1u);   // RNE
    return (short)(r >> 16);
}

__device__ __forceinline__ void gload_lds16(const void* g, void* l) {
    __builtin_amdgcn_global_load_lds(
        (const __attribute__((address_space(1))) void*)g,
        (__attribute__((address_space(3))) void*)l, 16, 0, 0);
}

// ---------------------------------------------------------------------------
// bf16 MFMA GEMM: C = relu(A @ W^T + bias). Tile 128x128, 4 waves, 16x16x32.
// A bf16 [nrows][lda] (lda in shorts; may be < KSTEPS*32: the k-overrun reads
// finite neighbor data which is multiplied by B's zero padding -> no effect).
// B bf16 [M][KSTEPS*32] zero-padded.
// ---------------------------------------------------------------------------
template<int KSTEPS, bool OUT_BF16>
__global__ __launch_bounds__(256)
void mfma_gemm(const short* __restrict__ A, int lda, const short* __restrict__ B,
               const float* __restrict__ bias, int nbias,
               void* __restrict__ Cout, int ldc, int ncols_store, int nrows)
{
    __shared__ short ldsA[128 * 32];
    __shared__ short ldsB[128 * 32];
    const int t    = threadIdx.x;
    const int lane = t & 63;
    const int wid  = t >> 6;
    const int rowBase = blockIdx.y * 128;
    const int colBase = blockIdx.x * 128;
    const int wrow = (wid >> 1) * 64;
    const int wcol = (wid & 1) * 64;

    const int q  = t & 3;    // 8-elem (16B) chunk within 32-wide k tile
    const int rl = t >> 2;   // 0..63

    f32x4 acc[4][4] = {};
    const int KPB = KSTEPS * 32;   // B row stride (padded)

    for (int ks = 0; ks < KSTEPS; ++ks) {
        const int k0 = ks * 32;

        #pragma unroll
        for (int i = 0; i < 2; ++i) {
            const short* srcB = B + (size_t)(colBase + rl + i * 64) * KPB + k0 + q * 8;
            gload_lds16(srcB, &ldsB[wid * 512 + i * 2048]);
        }
        #pragma unroll
        for (int i = 0; i < 2; ++i) {
            int grow = rowBase + rl + i * 64; if (grow > NN - 1) grow = NN - 1;
            const short* srcA = A + (size_t)grow * lda + k0 + q * 8;
            gload_lds16(srcA, &ldsA[wid * 512 + i * 2048]);
        }

        __syncthreads();

        {
            const int kb = lane >> 4;
            const int l16 = lane & 15;
            s16x8 a[4], b[4];
            #pragma unroll
            for (int m = 0; m < 4; ++m)
                a[m] = *(const s16x8*)&ldsA[(wrow + m * 16 + l16) * 32 + kb * 8];
            #pragma unroll
            for (int n = 0; n < 4; ++n)
                b[n] = *(const s16x8*)&ldsB[(wcol + n * 16 + l16) * 32 + kb * 8];
            #pragma unroll
            for (int m = 0; m < 4; ++m)
                #pragma unroll
                for (int n = 0; n < 4; ++n)
                    acc[m][n] = __builtin_amdgcn_mfma_f32_16x16x32_bf16(
                        a[m], b[n], acc[m][n], 0, 0, 0);
        }

        __syncthreads();
    }

    const int crow0 = (lane >> 4) * 4;
    const int ccol  = lane & 15;
    #pragma unroll
    for (int n = 0; n < 4; ++n) {
        int col = colBase + wcol + n * 16 + ccol;
        float bv = (col < nbias) ? bias[col] : 0.f;
        #pragma unroll
        for (int m = 0; m < 4; ++m) {
            #pragma unroll
            for (int j = 0; j < 4; ++j) {
                int row = rowBase + wrow + m * 16 + crow0 + j;
                if (row >= nrows) continue;
                float v = acc[m][n][j] + bv;
                v = fmaxf(v, 0.f);
                if (OUT_BF16) {
                    ((short*)Cout)[(size_t)row * ldc + col] = f2bf(v);
                } else if (col < ncols_store) {
                    ((float*)Cout)[(size_t)row * ldc + col] = v;
                }
            }
        }
    }
}

// ---------------------------------------------------------------------------
// x fp32 [N][500] -> bf16 [N][500] contiguous, 8 elems/thread
// ---------------------------------------------------------------------------
__global__ void convert_x_kernel(const float* __restrict__ in, short* __restrict__ out) {
    int idx = blockIdx.x * blockDim.x + threadIdx.x;
    if (idx >= (NN * 500) / 8) return;
    const float4* in4 = (const float4*)in;
    float4 a = in4[(size_t)idx * 2];
    float4 b = in4[(size_t)idx * 2 + 1];
    s16x8 s;
    s[0]=f2bf(a.x); s[1]=f2bf(a.y); s[2]=f2bf(a.z); s[3]=f2bf(a.w);
    s[4]=f2bf(b.x); s[5]=f2bf(b.y); s[6]=f2bf(b.z); s[7]=f2bf(b.w);
    *(s16x8*)&out[(size_t)idx * 8] = s;
}

__global__ void convert_w_kernel(const float* __restrict__ in, short* __restrict__ out,
                                 int R, int C, int Rp, int Cp) {
    int idx = blockIdx.x * blockDim.x + threadIdx.x;
    if (idx >= Rp * Cp) return;
    int r = idx / Cp, c = idx - r * Cp;
    float v = (r < R && c < C) ? in[r * C + c] : 0.f;
    out[idx] = f2bf(v);
}

// ---------------------------------------------------------------------------
// Graph build: CSR-by-dst with packed (src, norm) pairs
// ---------------------------------------------------------------------------
__global__ void deg_init_kernel(int* deg, int n) {
    int i = blockIdx.x * blockDim.x + threadIdx.x;
    if (i < n) deg[i] = 1;
}
__global__ void deg_count_kernel(const int* __restrict__ dst, int* deg, int e) {
    int i = blockIdx.x * blockDim.x + threadIdx.x;
    if (i < e) atomicAdd(&deg[dst[i]], 1);
}
__global__ void dinv_kernel(const int* __restrict__ deg, float* __restrict__ dinv,
                            float* __restrict__ dinv2, int n) {
    int i = blockIdx.x * blockDim.x + threadIdx.x;
    if (i < n) {
        float d = (float)deg[i];
        dinv[i] = rsqrtf(d);
        dinv2[i] = 1.0f / d;
    }
}
__global__ __launch_bounds__(256)
void scan1_kernel(const int* __restrict__ deg, int* __restrict__ row_ptr,
                  int* __restrict__ blockSums, int n) {
    __shared__ int sdata[256];
    const int base = blockIdx.x * 2048;
    const int t = threadIdx.x;
    int local[8];
    int s = 0;
    #pragma unroll
    for (int i = 0; i < 8; ++i) {
        int idx = base + t * 8 + i;
        int c = (idx < n) ? (deg[idx] - 1) : 0;
        local[i] = s;
        s += c;
    }
    sdata[t] = s;
    __syncthreads();
    for (int off = 1; off < 256; off <<= 1) {
        int v = (t >= off) ? sdata[t - off] : 0;
        __syncthreads();
        sdata[t] += v;
        __syncthreads();
    }
    int excl = (t == 0) ? 0 : sdata[t - 1];
    #pragma unroll
    for (int i = 0; i < 8; ++i) {
        int idx = base + t * 8 + i;
        if (idx < n) row_ptr[idx] = excl + local[i];
    }
    if (t == 255) blockSums[blockIdx.x] = sdata[255];
}
__global__ void scan2_kernel(int* blockSums, int nb) {
    if (threadIdx.x == 0 && blockIdx.x == 0) {
        int s = 0;
        for (int i = 0; i < nb; ++i) { int v = blockSums[i]; blockSums[i] = s; s += v; }
    }
}
__global__ void scan3_kernel(int* __restrict__ row_ptr, int* __restrict__ cursor,
                             const int* __restrict__ blockSums, int n, int e) {
    int i = blockIdx.x * blockDim.x + threadIdx.x;
    if (i < n) {
        int v = row_ptr[i] + blockSums[i >> 11];
        row_ptr[i] = v;
        cursor[i] = v;
    }
    if (i == 0) row_ptr[n] = e;
}
__global__ void fill_csr_kernel(const int* __restrict__ src, const int* __restrict__ dst,
                                const float* __restrict__ dinv, int* cursor,
                                int2* __restrict__ pairs, int e) {
    int i = blockIdx.x * blockDim.x + threadIdx.x;
    if (i < e) {
        int s = src[i], d = dst[i];
        int pos = atomicAdd(&cursor[d], 1);
        float nv = dinv[s] * dinv[d];
        pairs[pos] = make_int2(s, __float_as_int(nv));
    }
}

// ---------------------------------------------------------------------------
// APPNP step: float4 x 10 threads/node, 32 nodes/block, edge loop unrolled x4
// ---------------------------------------------------------------------------
__global__ __launch_bounds__(320)
void prop_kernel(const float4* __restrict__ hin4, const float4* __restrict__ h04,
                 const int* __restrict__ rowp, const int2* __restrict__ pairs,
                 const float* __restrict__ dinv2, float4* __restrict__ hout4, int n)
{
    const int t = threadIdx.x;
    const int vl = t / 10;
    const int f4 = t - vl * 10;
    const int v = blockIdx.x * 32 + vl;
    if (v >= n) return;
    const size_t base = (size_t)v * 10 + f4;

    float4 sf = hin4[base];
    const float dv = dinv2[v];
    float ax = dv * sf.x, ay = dv * sf.y, az = dv * sf.z, aw = dv * sf.w;

    int e = rowp[v];
    const int e1 = rowp[v + 1];

    for (; e + 4 <= e1; e += 4) {
        int2 p0 = pairs[e], p1 = pairs[e + 1], p2 = pairs[e + 2], p3 = pairs[e + 3];
        float4 g0 = hin4[(size_t)p0.x * 10 + f4];
        float4 g1 = hin4[(size_t)p1.x * 10 + f4];
        float4 g2 = hin4[(size_t)p2.x * 10 + f4];
        float4 g3 = hin4[(size_t)p3.x * 10 + f4];
        float w0 = __int_as_float(p0.y), w1 = __int_as_float(p1.y);
        float w2 = __int_as_float(p2.y), w3 = __int_as_float(p3.y);
        ax = fmaf(w0, g0.x, ax); ay = fmaf(w0, g0.y, ay);
        az = fmaf(w0, g0.z, az); aw = fmaf(w0, g0.w, aw);
        ax = fmaf(w1, g1.x, ax); ay = fmaf(w1, g1.y, ay);
        az = fmaf(w1, g1.z, az); aw = fmaf(w1, g1.w, aw);
        ax = fmaf(w2, g2.x, ax); ay = fmaf(w2, g2.y, ay);
        az = fmaf(w2, g2.z, az); aw = fmaf(w2, g2.w, aw);
        ax = fmaf(w3, g3.x, ax); ay = fmaf(w3, g3.y, ay);
        az = fmaf(w3, g3.z, az); aw = fmaf(w3, g3.w, aw);
    }
    for (; e < e1; ++e) {
        int2 p = pairs[e];
        float4 g = hin4[(size_t)p.x * 10 + f4];
        float w = __int_as_float(p.y);
        ax = fmaf(w, g.x, ax); ay = fmaf(w, g.y, ay);
        az = fmaf(w, g.z, az); aw = fmaf(w, g.w, aw);
    }

    float4 h0v = h04[base];
    float4 o;
    o.x = fmaf(0.9f, ax, 0.1f * h0v.x);
    o.y = fmaf(0.9f, ay, 0.1f * h0v.y);
    o.z = fmaf(0.9f, az, 0.1f * h0v.z);
    o.w = fmaf(0.9f, aw, 0.1f * h0v.w);
    hout4[base] = o;
}

// ---------------------------------------------------------------------------
extern "C" void kernel_launch(void* const* d_in, const int* in_sizes, int n_in,
                              void* d_out, int out_size, void* d_ws, size_t ws_size,
                              hipStream_t stream) {
    const float* x  = (const float*)d_in[0];
    const int* ei   = (const int*)d_in[1];
    const float* W0 = (const float*)d_in[2];
    const float* b0 = (const float*)d_in[3];
    const float* W1 = (const float*)d_in[4];
    const float* b1 = (const float*)d_in[5];
    const float* W2 = (const float*)d_in[6];
    const float* b2 = (const float*)d_in[7];
    float* out = (float*)d_out;
    char* ws = (char*)d_ws;

    const int* src = ei;
    const int* dst = ei + EE;

    // ---- Workspace layout with lifetime overlap (total 151.6 MB) ----
    // Phase 1 (MLP):  xb [0,100e6) ; h1b [100e6,151.2e6) ; weights [151.2e6,+360448)
    // Phase 2 (after GEMM0, region 0 reused): h2b, h0, hA, hB
    // Phase 3 (after GEMM1, region 100e6 reused): pairs + graph arrays
    short* xb   = (short*)(ws);                   // [N][500] bf16
    short* h1b  = (short*)(ws + 100000000);       // [N][256] bf16
    short* W0b  = (short*)(ws + 151200000);       // [256][512]
    short* W1b  = (short*)(ws + 151462144);       // [128][256]
    short* W2b  = (short*)(ws + 151527680);       // [128][128] (ends 151,560,448)

    short* h2b  = (short*)(ws);                   // [N][128] bf16 (reuse xb)
    float* h0   = (float*)(ws + 25600000);        // [N][40] f32
    float* hA   = (float*)(ws + 41600000);        // [N][40]
    float* hB   = (float*)(ws + 57600000);        // [N][40] (ends 73.6e6)

    int2*  pairs= (int2*) (ws + 100000000);       // [E] (reuse h1b)
    int*   deg  = (int*)  (ws + 112800000);       // [N]
    float* dinv = (float*)(ws + 113200000);       // [N]
    float* dnv2 = (float*)(ws + 113600000);       // [N]
    int*   rowp = (int*)  (ws + 114000000);       // [N+1]
    int*   curs = (int*)  (ws + 114400008);       // [N]
    int*   bsum = (int*)  (ws + 114800008);       // [4096]
    (void)ws_size; (void)in_sizes; (void)n_in; (void)out_size;

    // ---- conversions ----
    convert_x_kernel<<<((NN * 500 / 8) + 255) / 256, 256, 0, stream>>>(x, xb);
    convert_w_kernel<<<(256 * 512 + 255) / 256, 256, 0, stream>>>(W0, W0b, 256, 500, 256, 512);
    convert_w_kernel<<<(128 * 256 + 255) / 256, 256, 0, stream>>>(W1, W1b, 128, 256, 128, 256);
    convert_w_kernel<<<(128 * 128 + 255) / 256, 256, 0, stream>>>(W2, W2b, 40, 128, 128, 128);

    // ---- MLP encoder ----
    const int NBLK = (NN + 127) / 128;  // 782
    mfma_gemm<16, true ><<<dim3(2, NBLK), 256, 0, stream>>>(
        xb, 500, W0b, b0, 256, (void*)h1b, 256, 256, NN);
    mfma_gemm<8,  true ><<<dim3(1, NBLK), 256, 0, stream>>>(
        h1b, 256, W1b, b1, 128, (void*)h2b, 128, 128, NN);
    mfma_gemm<4,  false><<<dim3(1, NBLK), 256, 0, stream>>>(
        h2b, 128, W2b, b2, 40, (void*)h0, 40, 40, NN);

    // ---- graph build (after GEMM1: h1b region is dead) ----
    {
        int nb_n = (NN + 255) / 256;
        int nb_e = (EE + 255) / 256;
        deg_init_kernel<<<nb_n, 256, 0, stream>>>(deg, NN);
        deg_count_kernel<<<nb_e, 256, 0, stream>>>(dst, deg, EE);
        dinv_kernel<<<nb_n, 256, 0, stream>>>(deg, dinv, dnv2, NN);
        int nb_scan = (NN + 2047) / 2048;
        scan1_kernel<<<nb_scan, 256, 0, stream>>>(deg, rowp, bsum, NN);
        scan2_kernel<<<1, 64, 0, stream>>>(bsum, nb_scan);
        scan3_kernel<<<nb_n, 256, 0, stream>>>(rowp, curs, bsum, NN, EE);
        fill_csr_kernel<<<nb_e, 256, 0, stream>>>(src, dst, dinv, curs, pairs, EE);
    }

    // ---- APPNP propagation ----
    {
        dim3 blk(320);
        dim3 grd((NN + 31) / 32);  // 3125
        const float* hin = h0;
        for (int it = 0; it < KITER; ++it) {
            float* hout = (it == KITER - 1) ? out : ((it & 1) ? hB : hA);
            prop_kernel<<<grd, blk, 0, stream>>>(
                (const float4*)hin, (const float4*)h0, rowp, pairs, dnv2,
                (float4*)hout, NN);
            hin = hout;
        }
    }
}